// Round 8
// baseline (1746.387 us; speedup 1.0000x reference)
//
#include <hip/hip_runtime.h>
#include <hip/hip_bf16.h>
#include <cstdint>

// DecoderRNN: LSTM(31 steps, B=128, E=512, H=1024) + FC to V=32000.
// bf16 MFMA (fp32 accum), fp32 cell state in REGISTERS.
//   1) prep: bf16 weight conversion, embedding gather, bias sum, zero out[:,0,:]
//   2) Gx = X @ W_ih^T + (b_ih+b_hh)      [3968x4096x512]
//   3) ONE persistent kernel runs all 31 steps: 64 blocks, device-scope
//      spin grid-barrier between steps; Whh slab L2-resident per block;
//      K-loop = 4-buffer LDS pipeline, counted vmcnt + raw s_barrier
//      (no vmcnt(0) drains); XOR-swizzled LDS to kill bank conflicts.
//   4) out[:,1:,:] = Hseq @ fc_W^T + fc_b [3968x32000x1024, row-scatter,
//      XCD-chunk swizzle + GROUP_M raster for L2 reuse of fc_W panels]

typedef unsigned short u16;
typedef __attribute__((ext_vector_type(8))) short bf16x8;
typedef __attribute__((ext_vector_type(4))) float f32x4;

static constexpr int B_ = 128, T_ = 32, E_ = 512, H_ = 1024, V_ = 32000;
static constexpr int TS = T_ - 1;          // 31 time steps
static constexpr int M_SEQ = TS * B_;      // 3968
static constexpr int G4 = 4 * H_;          // 4096
static constexpr int NBLK = 64;            // persistent LSTM grid

__device__ __forceinline__ u16 f2bf(float x) {
  union { __hip_bfloat16 b; u16 u; } c; c.b = __float2bfloat16(x); return c.u;
}

__device__ __forceinline__ void gload_lds16(const void* g, void* l) {
  __builtin_amdgcn_global_load_lds(
      (const __attribute__((address_space(1))) unsigned int*)g,
      (__attribute__((address_space(3))) unsigned int*)l, 16, 0, 0);
}

__device__ __forceinline__ float sigm(float x) { return 1.f / (1.f + expf(-x)); }

// ---------------- prep kernels ----------------

__global__ void cvt_bf16x4(const float* __restrict__ s, u16* __restrict__ d, int n) {
  int i = (blockIdx.x * blockDim.x + threadIdx.x) * 4;
  if (i >= n) return;
  const float4 v = *(const float4*)(s + i);
  *(ushort4*)(d + i) = make_ushort4(f2bf(v.x), f2bf(v.y), f2bf(v.z), f2bf(v.w));
}

__global__ void addb(const float* __restrict__ a, const float* __restrict__ b,
                     float* __restrict__ o) {
  int i = blockIdx.x * blockDim.x + threadIdx.x;
  if (i < G4) o[i] = a[i] + b[i];
}

__global__ void gather_x(const int* __restrict__ cap, const float* __restrict__ emb,
                         u16* __restrict__ X) {
  int i4 = blockIdx.x * blockDim.x + threadIdx.x;   // over 3968*512/4
  if (i4 >= M_SEQ * (E_ / 4)) return;
  int i = i4 * 4;
  int tb = i >> 9;         // row in X: t*128 + b
  int e = i & (E_ - 1);
  int t = tb >> 7;
  int b = tb & 127;
  int row = cap[b * T_ + t];
  const float4 v = *(const float4*)(emb + (long)row * E_ + e);
  *(ushort4*)(X + i) = make_ushort4(f2bf(v.x), f2bf(v.y), f2bf(v.z), f2bf(v.w));
}

__global__ void hc_init(const float* __restrict__ f, u16* __restrict__ h,
                        unsigned* __restrict__ ctr) {
  int i = blockIdx.x * blockDim.x + threadIdx.x;
  if (i == 0) *ctr = 0u;                      // zero the grid-barrier counter
  if (i < B_ * H_) h[i] = f2bf(f[i]);
}

__global__ void zero_t0(float* __restrict__ out) {
  int i4 = blockIdx.x * blockDim.x + threadIdx.x;   // over 128*32000/4
  if (i4 >= B_ * (V_ / 4)) return;
  int b = i4 / (V_ / 4), v4 = i4 % (V_ / 4);
  *(float4*)(out + (long)b * T_ * V_ + v4 * 4) = make_float4(0.f, 0.f, 0.f, 0.f);
}

// ---------------- GEMM: C[M,N] = A[M,K] @ B[N,K]^T + bias[n] ----------------
// m97 structure: 128x128 tile, 4 waves 2x2 each 64x64, 16x16x32 bf16 MFMA,
// global_load_lds width-16 staging, 2-barrier K loop.
// SCATTER=1 remaps row m=(t*128+b) -> out row (b*32 + t + 1)  (fc projection).
// ORDER=1: m204 bijective XCD-chunk swizzle + GROUP_M=8 raster (B-panel reuse).

template<int SCATTER, int ORDER>
__global__ __launch_bounds__(256)
void gemm_bt(const u16* __restrict__ A, int lda,
             const u16* __restrict__ B, int ldb,
             float* __restrict__ C, long ldc,
             const float* __restrict__ bias,
             int K, int ntn)
{
  constexpr int BM = 128, BN = 128, NFR = 4;
  int mt, nt;
  if constexpr (ORDER == 1) {
    const int nwg = gridDim.x;
    const int nmt = nwg / ntn;
    const int xcd = blockIdx.x & 7, o = blockIdx.x >> 3;
    const int q = nwg >> 3, rr = nwg & 7;
    const int swz = (xcd < rr ? xcd * (q + 1) : rr * (q + 1) + (xcd - rr) * q) + o;
    constexpr int GM = 8;
    const int npg = GM * ntn;
    const int grp = swz / npg;
    const int first = grp * GM;
    const int gsz = min(GM, nmt - first);
    mt = first + (swz % npg) % gsz;
    nt = (swz % npg) / gsz;
  } else {
    mt = blockIdx.x / ntn; nt = blockIdx.x % ntn;
  }
  const int tid = threadIdx.x;
  const int wid = tid >> 6, lane = tid & 63;
  const int wm = (wid >> 1) * 64, wn = (wid & 1) * 64;
  const int l15 = lane & 15, l4 = lane >> 4;

  __shared__ __align__(16) u16 As[BM * 32];
  __shared__ __align__(16) u16 Bs[BN * 32];

  f32x4 acc[4][NFR] = {};

  const u16* Ag = A + (long)(mt * BM + (tid >> 2)) * lda + (tid & 3) * 8;
  const u16* Bg = B + (long)(nt * BN + (tid >> 2)) * ldb + (tid & 3) * 8;
  char* AsW = (char*)As + wid * 1024;
  char* BsW = (char*)Bs + wid * 1024;

  for (int kt = 0; kt < K; kt += 32) {
    gload_lds16(Ag + kt, AsW);
    gload_lds16(Ag + 64 * (long)lda + kt, AsW + 4096);
    gload_lds16(Bg + kt, BsW);
    gload_lds16(Bg + 64 * (long)ldb + kt, BsW + 4096);
    __syncthreads();   // compiler drains vmcnt before barrier

    const u16* Ab = As + (wm + l15) * 32 + l4 * 8;
    const u16* Bb = Bs + (wn + l15) * 32 + l4 * 8;
    bf16x8 af[4], bfr[NFR];
#pragma unroll
    for (int i = 0; i < 4; ++i) af[i] = *(const bf16x8*)(Ab + i * 16 * 32);
#pragma unroll
    for (int j = 0; j < NFR; ++j) bfr[j] = *(const bf16x8*)(Bb + j * 16 * 32);
#pragma unroll
    for (int i = 0; i < 4; ++i)
#pragma unroll
      for (int j = 0; j < NFR; ++j)
        acc[i][j] = __builtin_amdgcn_mfma_f32_16x16x32_bf16(af[i], bfr[j], acc[i][j], 0, 0, 0);
    __syncthreads();
  }

  // C/D layout: col = lane&15, row = (lane>>4)*4 + r  (m89/m91 verified)
  const int grow0 = mt * BM + wm + l4 * 4;
  const int gcol0 = nt * BN + wn + l15;
#pragma unroll
  for (int i = 0; i < 4; ++i) {
#pragma unroll
    for (int j = 0; j < NFR; ++j) {
      const int col = gcol0 + j * 16;
      const float bv = bias ? bias[col] : 0.0f;
#pragma unroll
      for (int r = 0; r < 4; ++r) {
        const int row = grow0 + i * 16 + r;
        float v = acc[i][j][r] + bv;
        long o;
        if constexpr (SCATTER) {
          const int t = row >> 7, b = row & 127;
          o = ((long)(b * T_ + t + 1)) * ldc + col;
        } else {
          o = (long)row * ldc + col;
        }
        C[o] = v;
      }
    }
  }
}

// ---------------- persistent LSTM: all 31 steps in one kernel ----------------
// 64 blocks x 256 thr. Block owns h-cols j0..j0+15 (x4 gates = 64 Whh rows).
// Per step: gates tile = h(128xK) @ Whh_slab(64xK)^T via 32 K-iters of a
// 4-buffer pipelined loop (counted vmcnt, raw s_barrier, no vmcnt(0) drains;
// lgkmcnt(0) on each barrier pins ds_read completion -> no buffer-reuse race),
// then in-register cell update (c lives in VGPRs across steps), h -> Hseq[t],
// then device-scope spin grid-barrier.

__device__ __forceinline__ void gridbar(unsigned* ctr, unsigned target, int tid) {
  __builtin_amdgcn_fence(__ATOMIC_RELEASE, "agent");
  __syncthreads();
  if (tid == 0) {
    __hip_atomic_fetch_add(ctr, 1u, __ATOMIC_RELAXED, __HIP_MEMORY_SCOPE_AGENT);
    while (__hip_atomic_load(ctr, __ATOMIC_RELAXED, __HIP_MEMORY_SCOPE_AGENT) < target)
      __builtin_amdgcn_s_sleep(2);
  }
  __syncthreads();
  __builtin_amdgcn_fence(__ATOMIC_ACQUIRE, "agent");
}

__global__ __launch_bounds__(256)
void lstm_persist(const u16* __restrict__ h0,      // 128x1024 bf16 (step-0 h)
                  const u16* __restrict__ Whh,     // 4096x1024 bf16
                  const float* __restrict__ feat,  // 128x1024 fp32 (c0)
                  const float* __restrict__ gx,    // 31x128x4096 fp32
                  u16* __restrict__ Hseq,          // 31x128x1024 bf16 out
                  unsigned* __restrict__ ctr)
{
  const int tid = threadIdx.x;
  const int wid = tid >> 6, lane = tid & 63;
  const int l15 = lane & 15, l4 = lane >> 4;
  const int j0 = blockIdx.x * 16;
  const int jj = j0 + l15;

  __shared__ __align__(16) u16 As[4][128 * 32];   // 32 KB (4 pipeline bufs)
  __shared__ __align__(16) u16 Bs[4][64 * 32];    // 16 KB

  // c state in registers for the whole sequence
  float creg[2][4];
#pragma unroll
  for (int mi = 0; mi < 2; ++mi)
#pragma unroll
    for (int r = 0; r < 4; ++r)
      creg[mi][r] = feat[(wid * 32 + mi * 16 + l4 * 4 + r) * H_ + jj];

  // --- staging maps (G21: linear LDS dest + inverse-swizzled global source) ---
  // LDS 16B-slot swizzle: phys_slot = logical_slot ^ ((row>>1)&3).
  const int src_kk = (((lane & 3) ^ ((lane >> 3) & 3))) * 8;        // elems
  // A: wave w stages rows 32w..32w+31 (2 gloads), dest = w*2048 (+1024)
  const long a_off = (long)(32 * wid + (lane >> 2)) * H_ + src_kk;
  // B: thread tid stages slab row br=tid>>2 -> Whh row (br>>4)*1024 + j0 + (br&15)
  const int br = tid >> 2;
  const long b_off = (long)((br >> 4) * H_ + j0 + (br & 15)) * H_ + src_kk;
  // reads: frag(row R, k-half l4) at byte R*64 + (l4 ^ ((R>>1)&3))*16;
  // for both A (R=32w+mi*16+l15) and B (R=g*16+l15): (R>>1)&3 == (l15>>1)&3.
  const int rd_sx = (l4 ^ ((l15 >> 1) & 3)) * 16;

  for (int t = 0; t < TS; ++t) {
    const u16* hsrc = (t == 0) ? h0 : Hseq + (size_t)(t - 1) * B_ * H_;
    const float* gxt = gx + (size_t)t * B_ * G4;

    f32x4 acc[2][4] = {};

    auto stage = [&](int kt2) {
      char* Ad = (char*)As[kt2 & 3] + wid * 2048;
      gload_lds16(hsrc + a_off + kt2 * 32, Ad);
      gload_lds16(hsrc + a_off + 16 * H_ + kt2 * 32, Ad + 1024);
      gload_lds16(Whh + b_off + kt2 * 32, (char*)Bs[kt2 & 3] + wid * 1024);
    };

    stage(0);
    stage(1);

#pragma unroll
    for (int kt = 0; kt < 32; ++kt) {
      if (kt + 2 < 32) stage(kt + 2);
      // counted vmcnt keeps 2 stages in flight across the barrier; lgkmcnt(0)
      // pins previous iter's ds_read completion (zero-cost: already consumed)
      // so no wave can see this iter's LDS overwrites hit a pending read.
      if (kt < 30)       asm volatile("s_waitcnt vmcnt(6) lgkmcnt(0)" ::: "memory");
      else if (kt == 30) asm volatile("s_waitcnt vmcnt(3) lgkmcnt(0)" ::: "memory");
      else               asm volatile("s_waitcnt vmcnt(0) lgkmcnt(0)" ::: "memory");
      asm volatile("s_barrier" ::: "memory");   // counted-vmcnt barrier, no drain

      const char* Ab = (const char*)As[kt & 3];
      const char* Bb = (const char*)Bs[kt & 3];
      bf16x8 af[2], bfr[4];
#pragma unroll
      for (int mi = 0; mi < 2; ++mi)
        af[mi] = *(const bf16x8*)(Ab + (32 * wid + mi * 16 + l15) * 64 + rd_sx);
#pragma unroll
      for (int g = 0; g < 4; ++g)
        bfr[g] = *(const bf16x8*)(Bb + (g * 16 + l15) * 64 + rd_sx);
#pragma unroll
      for (int mi = 0; mi < 2; ++mi)
#pragma unroll
        for (int g = 0; g < 4; ++g)
          acc[mi][g] = __builtin_amdgcn_mfma_f32_16x16x32_bf16(af[mi], bfr[g], acc[mi][g], 0, 0, 0);
    }

    // in-register cell update; acc[mi][g][r] holds gate g preact for (m, jj)
    u16* hrow = Hseq + (size_t)t * B_ * H_;
#pragma unroll
    for (int mi = 0; mi < 2; ++mi) {
#pragma unroll
      for (int r = 0; r < 4; ++r) {
        const int m = wid * 32 + mi * 16 + l4 * 4 + r;
        const float* gr = gxt + (long)m * G4 + jj;
        float gi = sigm(acc[mi][0][r] + gr[0]);
        float gf = sigm(acc[mi][1][r] + gr[H_]);
        float gg = tanhf(acc[mi][2][r] + gr[2 * H_]);
        float go = sigm(acc[mi][3][r] + gr[3 * H_]);
        float cn = gf * creg[mi][r] + gi * gg;
        creg[mi][r] = cn;
        hrow[m * H_ + jj] = f2bf(go * tanhf(cn));
      }
    }

    if (t != TS - 1) gridbar(ctr, (unsigned)((t + 1) * NBLK), tid);
  }
}

// ---------------- launch ----------------

extern "C" void kernel_launch(void* const* d_in, const int* in_sizes, int n_in,
                              void* d_out, int out_size, void* d_ws, size_t ws_size,
                              hipStream_t stream) {
  const float* features = (const float*)d_in[0];
  const int*   captions = (const int*)d_in[1];
  const float* embed    = (const float*)d_in[2];
  const float* W_ih     = (const float*)d_in[3];
  const float* W_hh     = (const float*)d_in[4];
  const float* b_ih     = (const float*)d_in[5];
  const float* b_hh     = (const float*)d_in[6];
  const float* fc_W     = (const float*)d_in[7];
  const float* fc_b     = (const float*)d_in[8];
  float* out = (float*)d_out;

  size_t off = 0;
  auto alloc = [&](size_t bytes) {
    void* p = (char*)d_ws + off;
    off += (bytes + 255) & ~(size_t)255;
    return p;
  };
  u16*  Wih_b = (u16*)alloc((size_t)G4 * E_ * 2);
  u16*  Whh_b = (u16*)alloc((size_t)G4 * H_ * 2);
  u16*  fcW_b = (u16*)alloc((size_t)V_ * H_ * 2);
  u16*  Xb    = (u16*)alloc((size_t)M_SEQ * E_ * 2);
  u16*  Hseq  = (u16*)alloc((size_t)M_SEQ * H_ * 2);
  u16*  hb0   = (u16*)alloc((size_t)B_ * H_ * 2);
  float* Gx   = (float*)alloc((size_t)M_SEQ * G4 * 4);
  float* bsum = (float*)alloc((size_t)G4 * 4);
  unsigned* ctr = (unsigned*)alloc(256);
  if (off > ws_size) return;   // workspace too small -> fail validation loudly

  // prep
  cvt_bf16x4<<<(G4 * E_ / 4 + 255) / 256, 256, 0, stream>>>(W_ih, Wih_b, G4 * E_);
  cvt_bf16x4<<<(G4 * H_ / 4 + 255) / 256, 256, 0, stream>>>(W_hh, Whh_b, G4 * H_);
  cvt_bf16x4<<<(V_ * H_ / 4 + 255) / 256, 256, 0, stream>>>(fc_W, fcW_b, V_ * H_);
  addb<<<(G4 + 255) / 256, 256, 0, stream>>>(b_ih, b_hh, bsum);
  gather_x<<<(M_SEQ * E_ / 4 + 255) / 256, 256, 0, stream>>>(captions, embed, Xb);
  hc_init<<<(B_ * H_ + 255) / 256, 256, 0, stream>>>(features, hb0, ctr);
  zero_t0<<<(B_ * V_ / 4 + 255) / 256, 256, 0, stream>>>(out);

  // Gx = X @ W_ih^T + bsum   (M=3968, N=4096, K=512)
  gemm_bt<0, 0><<<(M_SEQ / 128) * (G4 / 128), 256, 0, stream>>>(
      Xb, E_, Wih_b, E_, Gx, G4, bsum, E_, G4 / 128);

  // all 31 LSTM steps in one persistent kernel
  lstm_persist<<<NBLK, 256, 0, stream>>>(hb0, Whh_b, features, Gx, Hseq, ctr);

  // out[:,1:,:] = Hseq @ fc_W^T + fc_b   (M=3968, N=32000, K=1024)
  gemm_bt<1, 1><<<(M_SEQ / 128) * (V_ / 128), 256, 0, stream>>>(
      Hseq, H_, fcW_b, H_, out, V_, fc_b, H_, V_ / 128);
}